// Round 1
// baseline (403.333 us; speedup 1.0000x reference)
//
#include <hip/hip_runtime.h>
#include <stdint.h>

#define SEQ 4096
#define DM 768
#define NH 12
#define HD 64

typedef __attribute__((ext_vector_type(8))) short bf8;
typedef __attribute__((ext_vector_type(4))) float f4;

static __device__ __forceinline__ f4 mfma_bf16(bf8 a, bf8 b, f4 c) {
  return __builtin_amdgcn_mfma_f32_16x16x32_bf16(a, b, c, 0, 0, 0);
}

// RNE float->bf16 (bit pattern)
static __device__ __forceinline__ unsigned short f2bf(float f) {
  unsigned int u = __float_as_uint(f);
  u += 0x7FFFu + ((u >> 16) & 1u);
  return (unsigned short)(u >> 16);
}

static __device__ __forceinline__ void gload_lds16(const void* g, void* l) {
  __builtin_amdgcn_global_load_lds(
      (const __attribute__((address_space(1))) void*)g,
      (__attribute__((address_space(3))) void*)l, 16, 0, 0);
}

// ---- cast x (fp32) -> bf16, 4 elems/thread -------------------------------
__global__ __launch_bounds__(256) void k_cvt(const float* __restrict__ x,
                                             unsigned short* __restrict__ xb) {
  int i = (blockIdx.x * 256 + threadIdx.x) * 4;
  float4 v = *reinterpret_cast<const float4*>(x + i);
  ushort4 o;
  o.x = f2bf(v.x); o.y = f2bf(v.y); o.z = f2bf(v.z); o.w = f2bf(v.w);
  *reinterpret_cast<ushort4*>(xb + i) = o;
}

// ---- transpose+cast the 4 weight matrices: WT[z][n][k] = bf16(W[k][n]) ----
__global__ __launch_bounds__(256) void k_tw(const float* __restrict__ w0,
                                            const float* __restrict__ w1,
                                            const float* __restrict__ w2,
                                            const float* __restrict__ w3,
                                            unsigned short* __restrict__ wt) {
  const float* W = blockIdx.z == 0 ? w0 : blockIdx.z == 1 ? w1
                 : blockIdx.z == 2 ? w2 : w3;
  unsigned short* WT = wt + (size_t)blockIdx.z * DM * DM;
  __shared__ float t[32][33];
  int c0 = blockIdx.x * 32, r0 = blockIdx.y * 32;
  int lx = threadIdx.x & 31, ly = threadIdx.x >> 5;
#pragma unroll
  for (int rr = 0; rr < 32; rr += 8)
    t[ly + rr][lx] = W[(size_t)(r0 + ly + rr) * DM + c0 + lx];
  __syncthreads();
#pragma unroll
  for (int rr = 0; rr < 32; rr += 8)
    WT[(size_t)(c0 + ly + rr) * DM + r0 + lx] = f2bf(t[lx][ly + rr]);
}

// ---- bf16 MFMA GEMM: C[M=4096][N=768] = A[4096][768] @ Bt[768][768]^T ----
// BM=128 BN=64 BK=32, 4 waves (2x2), wave tile 64x32.
// MODE 0: store bf16 [row][768]   (Q, K)
// MODE 1: store bf16 transposed Vt[col][4096]  (V, col = h*64+d)
// MODE 2: store fp32 [row][768] + bias[col]    (out-proj)
template <int MODE>
__global__ __launch_bounds__(256) void k_gemm(const unsigned short* __restrict__ A,
                                              const unsigned short* __restrict__ Bt,
                                              void* __restrict__ Cout,
                                              const float* __restrict__ bias) {
  constexpr int K = DM;
  __shared__ unsigned short sA[128 * 32];
  __shared__ unsigned short sB[64 * 32];
  const int t = threadIdx.x, lane = t & 63, w = t >> 6;
  const int wr = w >> 1, wc = w & 1;
  const int c = lane & 15, g = lane >> 4;
  const int brow = blockIdx.x * 128, bcol = blockIdx.y * 64;
  f4 acc[4][2] = {};
  for (int k0 = 0; k0 < K; k0 += 32) {
    // stage A tile [128][32] (8 x 1KB wave-slots), XOR-swizzled 16B slots
#pragma unroll
    for (int i = 0; i < 2; ++i) {
      int slot = w * 2 + i;
      int chunk = slot * 64 + lane;
      int row = chunk >> 2;
      int sl = (chunk & 3) ^ ((row >> 1) & 3);
      gload_lds16(A + (size_t)(brow + row) * K + k0 + sl * 8, &sA[slot * 512]);
    }
    {  // stage Bt tile [64][32] (4 x 1KB wave-slots)
      int chunk = w * 64 + lane;
      int row = chunk >> 2;
      int sl = (chunk & 3) ^ ((row >> 1) & 3);
      gload_lds16(Bt + (size_t)(bcol + row) * K + k0 + sl * 8, &sB[w * 512]);
    }
    __syncthreads();
    bf8 af[4], bfr[2];
#pragma unroll
    for (int m = 0; m < 4; ++m) {
      int row = wr * 64 + m * 16 + c;
      int off = row * 64 + ((g * 16) ^ (((row >> 1) & 3) << 4));
      af[m] = *reinterpret_cast<const bf8*>(reinterpret_cast<const char*>(sA) + off);
    }
#pragma unroll
    for (int n = 0; n < 2; ++n) {
      int row = wc * 32 + n * 16 + c;
      int off = row * 64 + ((g * 16) ^ (((row >> 1) & 3) << 4));
      bfr[n] = *reinterpret_cast<const bf8*>(reinterpret_cast<const char*>(sB) + off);
    }
#pragma unroll
    for (int m = 0; m < 4; ++m)
#pragma unroll
      for (int n = 0; n < 2; ++n)
        acc[m][n] = mfma_bf16(af[m], bfr[n], acc[m][n]);
    __syncthreads();
  }
  // epilogue: C/D layout col=lane&15, row=(lane>>4)*4+r
#pragma unroll
  for (int m = 0; m < 4; ++m) {
#pragma unroll
    for (int n = 0; n < 2; ++n) {
      int col = bcol + wc * 32 + n * 16 + c;
      int row0 = brow + wr * 64 + m * 16 + g * 4;
      if (MODE == 0) {
        unsigned short* C = (unsigned short*)Cout;
#pragma unroll
        for (int r = 0; r < 4; ++r)
          C[(size_t)(row0 + r) * DM + col] = f2bf(acc[m][n][r]);
      } else if (MODE == 1) {
        unsigned short* C = (unsigned short*)Cout;
        ushort4 p;
        p.x = f2bf(acc[m][n][0]); p.y = f2bf(acc[m][n][1]);
        p.z = f2bf(acc[m][n][2]); p.w = f2bf(acc[m][n][3]);
        *reinterpret_cast<ushort4*>(C + (size_t)col * SEQ + row0) = p;
      } else {
        float* C = (float*)Cout;
#pragma unroll
        for (int r = 0; r < 4; ++r)
          C[(size_t)(row0 + r) * DM + col] = acc[m][n][r] + bias[col];
      }
    }
  }
}

// ---- causal flash attention: 1 wave per (16 q-rows, head) ----------------
// Qb,Kb: bf16 [4096][768]; Vt: bf16 [12*64][4096]; ctx out bf16 [4096][768]
__global__ __launch_bounds__(64) void k_attn(const unsigned short* __restrict__ Qb,
                                             const unsigned short* __restrict__ Kb,
                                             const unsigned short* __restrict__ Vt,
                                             unsigned short* __restrict__ ctx) {
  const int lane = threadIdx.x;
  const int c = lane & 15, g = lane >> 4;
  const int qblk = blockIdx.x & 255;
  const int h = blockIdx.x >> 8;
  const int q0 = qblk * 16;
  __shared__ unsigned short P[16 * 40];  // 16 q-rows x 32 k (+8 pad)
  const unsigned short* qp = Qb + (size_t)(q0 + c) * DM + h * HD + g * 8;
  bf8 qf0 = *reinterpret_cast<const bf8*>(qp);
  bf8 qf1 = *reinterpret_cast<const bf8*>(qp + 32);
  f4 of[4] = {};
  float mr[4] = {-1e30f, -1e30f, -1e30f, -1e30f};
  float lr[4] = {0.f, 0.f, 0.f, 0.f};
  const float cs = 0.1803368801f;  // log2(e) / sqrt(64)
  const int kmax = q0 + 16;
  for (int k0 = 0; k0 < kmax; k0 += 32) {
    f4 s0 = {}, s1 = {};
    {
      const unsigned short* kp = Kb + (size_t)(k0 + c) * DM + h * HD + g * 8;
      s0 = mfma_bf16(qf0, *reinterpret_cast<const bf8*>(kp), s0);
      s0 = mfma_bf16(qf1, *reinterpret_cast<const bf8*>(kp + 32), s0);
    }
    if (k0 + 16 < kmax) {
      const unsigned short* kp = Kb + (size_t)(k0 + 16 + c) * DM + h * HD + g * 8;
      s1 = mfma_bf16(qf0, *reinterpret_cast<const bf8*>(kp), s1);
      s1 = mfma_bf16(qf1, *reinterpret_cast<const bf8*>(kp + 32), s1);
    }
#pragma unroll
    for (int r = 0; r < 4; ++r) {
      int q = q0 + g * 4 + r;
      float a = (k0 + c > q) ? -1e30f : s0[r];
      float b = (k0 + 16 + c > q) ? -1e30f : s1[r];
      float mn = fmaxf(mr[r], fmaxf(a, b));
      mn = fmaxf(mn, __shfl_xor(mn, 1));
      mn = fmaxf(mn, __shfl_xor(mn, 2));
      mn = fmaxf(mn, __shfl_xor(mn, 4));
      mn = fmaxf(mn, __shfl_xor(mn, 8));
      float al = exp2f((mr[r] - mn) * cs);
      float pa = exp2f((a - mn) * cs);
      float pb = exp2f((b - mn) * cs);
      mr[r] = mn;
      float rs = pa + pb;
      rs += __shfl_xor(rs, 1);
      rs += __shfl_xor(rs, 2);
      rs += __shfl_xor(rs, 4);
      rs += __shfl_xor(rs, 8);
      lr[r] = lr[r] * al + rs;
      of[0][r] *= al; of[1][r] *= al; of[2][r] *= al; of[3][r] *= al;
      P[(g * 4 + r) * 40 + c] = f2bf(pa);
      P[(g * 4 + r) * 40 + 16 + c] = f2bf(pb);
    }
    // P: C-layout -> A-layout via LDS (single wave; DS ops in-order)
    bf8 pf = *reinterpret_cast<const bf8*>(&P[c * 40 + g * 8]);
#pragma unroll
    for (int n = 0; n < 4; ++n) {
      const unsigned short* vp =
          Vt + (size_t)(h * HD + n * 16 + c) * SEQ + k0 + g * 8;
      of[n] = mfma_bf16(pf, *reinterpret_cast<const bf8*>(vp), of[n]);
    }
  }
#pragma unroll
  for (int r = 0; r < 4; ++r) {
    float inv = 1.f / lr[r];
    size_t row = q0 + g * 4 + r;
#pragma unroll
    for (int n = 0; n < 4; ++n)
      ctx[row * DM + h * HD + n * 16 + c] = f2bf(of[n][r] * inv);
  }
}

extern "C" void kernel_launch(void* const* d_in, const int* in_sizes, int n_in,
                              void* d_out, int out_size, void* d_ws, size_t ws_size,
                              hipStream_t stream) {
  const float* x  = (const float*)d_in[0];
  const float* Wq = (const float*)d_in[1];
  const float* Wk = (const float*)d_in[2];
  const float* Wv = (const float*)d_in[3];
  const float* Wo = (const float*)d_in[4];
  const float* bo = (const float*)d_in[5];

  unsigned short* xb = (unsigned short*)d_ws;                 // [4096][768] bf16
  unsigned short* wt = xb + (size_t)SEQ * DM;                 // 4x [768][768] bf16 (W^T)
  unsigned short* Qb = wt + (size_t)4 * DM * DM;              // [4096][768]
  unsigned short* Kb = Qb + (size_t)SEQ * DM;                 // [4096][768]
  unsigned short* Vt = Kb + (size_t)SEQ * DM;                 // [768][4096] (per-head d-major)
  unsigned short* cx = Vt + (size_t)SEQ * DM;                 // [4096][768]

  k_cvt<<<(SEQ * DM) / 1024, 256, 0, stream>>>(x, xb);
  k_tw<<<dim3(24, 24, 4), 256, 0, stream>>>(Wq, Wk, Wv, Wo, wt);
  dim3 gg(SEQ / 128, DM / 64);
  k_gemm<0><<<gg, 256, 0, stream>>>(xb, wt, Qb, nullptr);
  k_gemm<0><<<gg, 256, 0, stream>>>(xb, wt + (size_t)DM * DM, Kb, nullptr);
  k_gemm<1><<<gg, 256, 0, stream>>>(xb, wt + (size_t)2 * DM * DM, Vt, nullptr);
  k_attn<<<(SEQ / 16) * NH, 64, 0, stream>>>(Qb, Kb, Vt, cx);
  k_gemm<2><<<gg, 256, 0, stream>>>(cx, wt + (size_t)3 * DM * DM, d_out, bo);
}

// Round 3
// 239.658 us; speedup vs baseline: 1.6830x; 1.6830x over previous
//
#include <hip/hip_runtime.h>
#include <stdint.h>

#define SEQ 4096
#define DM 768
#define NH 12
#define HD 64

typedef __attribute__((ext_vector_type(8))) short bf8;
typedef __attribute__((ext_vector_type(4))) float f4;
typedef __attribute__((ext_vector_type(16))) float f32x16;

static __device__ __forceinline__ f4 mfma_bf16(bf8 a, bf8 b, f4 c) {
  return __builtin_amdgcn_mfma_f32_16x16x32_bf16(a, b, c, 0, 0, 0);
}
static __device__ __forceinline__ f32x16 mfma32(bf8 a, bf8 b, f32x16 c) {
  return __builtin_amdgcn_mfma_f32_32x32x16_bf16(a, b, c, 0, 0, 0);
}

// RNE float->bf16 (bit pattern)
static __device__ __forceinline__ unsigned short f2bf(float f) {
  unsigned int u = __float_as_uint(f);
  u += 0x7FFFu + ((u >> 16) & 1u);
  return (unsigned short)(u >> 16);
}

// packed f32 pair -> bf16 pair (lo in low 16, hi in high 16)
static __device__ __forceinline__ unsigned int cvtpk(float lo, float hi) {
  unsigned int r;
  asm("v_cvt_pk_bf16_f32 %0, %1, %2" : "=v"(r) : "v"(lo), "v"(hi));
  return r;
}

static __device__ __forceinline__ void gload_lds16(const void* g, void* l) {
  __builtin_amdgcn_global_load_lds(
      (const __attribute__((address_space(1))) void*)g,
      (__attribute__((address_space(3))) void*)l, 16, 0, 0);
}

// ---- cast x (fp32) -> bf16 -----------------------------------------------
__global__ __launch_bounds__(256) void k_cvt(const float* __restrict__ x,
                                             unsigned short* __restrict__ xb) {
  int i = (blockIdx.x * 256 + threadIdx.x) * 4;
  float4 v = *reinterpret_cast<const float4*>(x + i);
  ushort4 o;
  o.x = f2bf(v.x); o.y = f2bf(v.y); o.z = f2bf(v.z); o.w = f2bf(v.w);
  *reinterpret_cast<ushort4*>(xb + i) = o;
}

// ---- transpose+cast weights: WT[z][n][k] = bf16(W[k][n]) -----------------
__global__ __launch_bounds__(256) void k_tw(const float* __restrict__ w0,
                                            const float* __restrict__ w1,
                                            const float* __restrict__ w2,
                                            const float* __restrict__ w3,
                                            unsigned short* __restrict__ wt) {
  const float* W = blockIdx.z == 0 ? w0 : blockIdx.z == 1 ? w1
                 : blockIdx.z == 2 ? w2 : w3;
  unsigned short* WT = wt + (size_t)blockIdx.z * DM * DM;
  __shared__ float t[32][33];
  int c0 = blockIdx.x * 32, r0 = blockIdx.y * 32;
  int lx = threadIdx.x & 31, ly = threadIdx.x >> 5;
#pragma unroll
  for (int rr = 0; rr < 32; rr += 8)
    t[ly + rr][lx] = W[(size_t)(r0 + ly + rr) * DM + c0 + lx];
  __syncthreads();
#pragma unroll
  for (int rr = 0; rr < 32; rr += 8)
    WT[(size_t)(c0 + ly + rr) * DM + r0 + lx] = f2bf(t[lx][ly + rr]);
}

// ---- bf16 MFMA GEMM: C[4096][768] = A[4096][768] @ Bt[768][768]^T --------
// MODE 0: store bf16 [row][768] * scale   (Q gets softmax scale folded in, K scale=1)
// MODE 1: store bf16 transposed Vt[col][4096]
// MODE 2: store fp32 [row][768] + bias[col]
template <int MODE>
__global__ __launch_bounds__(256) void k_gemm(const unsigned short* __restrict__ A,
                                              const unsigned short* __restrict__ Bt,
                                              void* __restrict__ Cout,
                                              const float* __restrict__ bias,
                                              float scale) {
  constexpr int K = DM;
  __shared__ unsigned short sA[128 * 32];
  __shared__ unsigned short sB[64 * 32];
  const int t = threadIdx.x, lane = t & 63, w = t >> 6;
  const int wr = w >> 1, wc = w & 1;
  const int c = lane & 15, g = lane >> 4;
  const int brow = blockIdx.x * 128, bcol = blockIdx.y * 64;
  f4 acc[4][2] = {};
  for (int k0 = 0; k0 < K; k0 += 32) {
#pragma unroll
    for (int i = 0; i < 2; ++i) {
      int slot = w * 2 + i;
      int chunk = slot * 64 + lane;
      int row = chunk >> 2;
      int sl = (chunk & 3) ^ ((row >> 1) & 3);
      gload_lds16(A + (size_t)(brow + row) * K + k0 + sl * 8, &sA[slot * 512]);
    }
    {
      int chunk = w * 64 + lane;
      int row = chunk >> 2;
      int sl = (chunk & 3) ^ ((row >> 1) & 3);
      gload_lds16(Bt + (size_t)(bcol + row) * K + k0 + sl * 8, &sB[w * 512]);
    }
    __syncthreads();
    bf8 af[4], bfr[2];
#pragma unroll
    for (int m = 0; m < 4; ++m) {
      int row = wr * 64 + m * 16 + c;
      int off = row * 64 + ((g * 16) ^ (((row >> 1) & 3) << 4));
      af[m] = *reinterpret_cast<const bf8*>(reinterpret_cast<const char*>(sA) + off);
    }
#pragma unroll
    for (int n = 0; n < 2; ++n) {
      int row = wc * 32 + n * 16 + c;
      int off = row * 64 + ((g * 16) ^ (((row >> 1) & 3) << 4));
      bfr[n] = *reinterpret_cast<const bf8*>(reinterpret_cast<const char*>(sB) + off);
    }
#pragma unroll
    for (int m = 0; m < 4; ++m)
#pragma unroll
      for (int n = 0; n < 2; ++n)
        acc[m][n] = mfma_bf16(af[m], bfr[n], acc[m][n]);
    __syncthreads();
  }
#pragma unroll
  for (int m = 0; m < 4; ++m) {
#pragma unroll
    for (int n = 0; n < 2; ++n) {
      int col = bcol + wc * 32 + n * 16 + c;
      int row0 = brow + wr * 64 + m * 16 + g * 4;
      if (MODE == 0) {
        unsigned short* C = (unsigned short*)Cout;
#pragma unroll
        for (int r = 0; r < 4; ++r)
          C[(size_t)(row0 + r) * DM + col] = f2bf(acc[m][n][r] * scale);
      } else if (MODE == 1) {
        unsigned short* C = (unsigned short*)Cout;
        ushort4 p;
        p.x = f2bf(acc[m][n][0]); p.y = f2bf(acc[m][n][1]);
        p.z = f2bf(acc[m][n][2]); p.w = f2bf(acc[m][n][3]);
        *reinterpret_cast<ushort4*>(C + (size_t)col * SEQ + row0) = p;
      } else {
        float* C = (float*)Cout;
#pragma unroll
        for (int r = 0; r < 4; ++r)
          C[(size_t)(row0 + r) * DM + col] = acc[m][n][r] + bias[col];
      }
    }
  }
}

// ---- causal flash attention, swapped-operand 32x32 form ------------------
// 2 waves/block, one 32-row q-tile per block, split-K (even/odd k-tiles).
// Qb pre-scaled by log2(e)/sqrt(HD). Vt: [12*64][4096].
__global__ __launch_bounds__(128) void k_attn(const unsigned short* __restrict__ Qb,
                                              const unsigned short* __restrict__ Kb,
                                              const unsigned short* __restrict__ Vt,
                                              unsigned short* __restrict__ ctx) {
  const int lane = threadIdx.x & 63;
  const int w = threadIdx.x >> 6;  // k-split index
  const int ql = lane & 31, hi = lane >> 5;
  const int qt = (int)gridDim.x - 1 - (int)blockIdx.x;  // longest blocks first
  const int h = blockIdx.y;
  const int q0 = qt * 32;
  const int qg = q0 + ql;
  const size_t hd = (size_t)h * HD;

  __shared__ float sO[2][64][32];
  __shared__ float sM[2][32];
  __shared__ float sL[2][32];

  // Q as B-fragments: B[d][q], col=q=lane&31, k(d)=8*hi+j
  bf8 qf[4];
  {
    const unsigned short* qp = Qb + (size_t)qg * DM + hd + hi * 8;
#pragma unroll
    for (int d = 0; d < 4; ++d)
      qf[d] = *reinterpret_cast<const bf8*>(qp + d * 16);
  }

  f32x16 o0 = {}, o1 = {};
  float m = -1e30f, l = 0.f;
  const int ntiles = q0 / 32 + 1;

  for (int t = w; t < ntiles; t += 2) {
    const int k0 = t * 32;
    // S^T[k][q] = K(32k x 16d) x Q(16d x 32q), accumulated over 4 d-steps
    f32x16 s = {};
    {
      const unsigned short* kp = Kb + (size_t)(k0 + ql) * DM + hd + hi * 8;
#pragma unroll
      for (int d = 0; d < 4; ++d)
        s = mfma32(*reinterpret_cast<const bf8*>(kp + d * 16), qf[d], s);
    }
    // V^T A-fragments for this tile (independent of softmax; issue early)
    bf8 vf[2][2];
    {
      const unsigned short* vp = Vt + (hd + ql) * SEQ + k0 + hi * 8;
#pragma unroll
      for (int kh = 0; kh < 2; ++kh) {
        vf[kh][0] = *reinterpret_cast<const bf8*>(vp + kh * 16);
        vf[kh][1] = *reinterpret_cast<const bf8*>(vp + (size_t)32 * SEQ + kh * 16);
      }
    }
    if (t == ntiles - 1) {  // diagonal tile: causal mask
#pragma unroll
      for (int r = 0; r < 16; ++r) {
        int kr = k0 + (r & 3) + 8 * (r >> 2) + 4 * hi;
        s[r] = (kr > qg) ? -1e30f : s[r];
      }
    }
    // online softmax (scores already in log2 scale)
    float tm = s[0];
#pragma unroll
    for (int r = 1; r < 16; ++r) tm = fmaxf(tm, s[r]);
    tm = fmaxf(tm, __shfl_xor(tm, 32));
    float mn = fmaxf(m, tm);
    float al = __builtin_amdgcn_exp2f(m - mn);
    m = mn;
    float p[16];
    float ls = 0.f;
#pragma unroll
    for (int r = 0; r < 16; ++r) {
      p[r] = __builtin_amdgcn_exp2f(s[r] - mn);
      ls += p[r];
    }
    ls += __shfl_xor(ls, 32);
    l = l * al + ls;
#pragma unroll
    for (int r = 0; r < 16; ++r) { o0[r] *= al; o1[r] *= al; }
    // P^T -> B-fragments via cvt_pk + permlane32_swap.
    // swap(vdst=A, vsrc=B): vdst upper-32-lanes <-> vsrc lower-32-lanes.
    // lane(q,hi) owns kloc {0-3,8-11}+4hi; B-frag needs kloc 8hi+{0..7}.
    bf8 pf[2];
#pragma unroll
    for (int kh = 0; kh < 2; ++kh) {
      unsigned int A0 = cvtpk(p[kh * 8 + 0], p[kh * 8 + 1]);
      unsigned int A1 = cvtpk(p[kh * 8 + 2], p[kh * 8 + 3]);
      unsigned int B0 = cvtpk(p[kh * 8 + 4], p[kh * 8 + 5]);
      unsigned int B1 = cvtpk(p[kh * 8 + 6], p[kh * 8 + 7]);
      asm volatile("v_permlane32_swap_b32 %0, %1" : "+v"(A0), "+v"(B0));
      asm volatile("v_permlane32_swap_b32 %0, %1" : "+v"(A1), "+v"(B1));
      uint4 wds = {A0, A1, B0, B1};
      pf[kh] = *reinterpret_cast<bf8*>(&wds);
    }
    // O^T[d][q] += V^T(32d x 16k) x P^T(16k x 32q)
#pragma unroll
    for (int kh = 0; kh < 2; ++kh) {
      o0 = mfma32(vf[kh][0], pf[kh], o0);
      o1 = mfma32(vf[kh][1], pf[kh], o1);
    }
  }

  // ---- split-K merge via LDS ----
#pragma unroll
  for (int r = 0; r < 16; ++r) {
    int dr = (r & 3) + 8 * (r >> 2) + 4 * hi;
    sO[w][dr][ql] = o0[r];
    sO[w][32 + dr][ql] = o1[r];
  }
  if (hi == 0) { sM[w][ql] = m; sL[w][ql] = l; }
  __syncthreads();
  float m0 = sM[0][ql], m1 = sM[1][ql];
  float mn = fmaxf(m0, m1);
  float a0 = __builtin_amdgcn_exp2f(m0 - mn);
  float a1 = __builtin_amdgcn_exp2f(m1 - mn);
  float inv = 1.f / (sL[0][ql] * a0 + sL[1][ql] * a1);
  a0 *= inv; a1 *= inv;
  const int db = w * 32 + hi * 16;  // this half-wave's 16 d's
  unsigned short* cp = ctx + (size_t)qg * DM + hd + db;
#pragma unroll
  for (int d = 0; d < 16; d += 2) {
    float v0 = sO[0][db + d][ql] * a0 + sO[1][db + d][ql] * a1;
    float v1 = sO[0][db + d + 1][ql] * a0 + sO[1][db + d + 1][ql] * a1;
    *reinterpret_cast<unsigned int*>(cp + d) = cvtpk(v0, v1);
  }
}

extern "C" void kernel_launch(void* const* d_in, const int* in_sizes, int n_in,
                              void* d_out, int out_size, void* d_ws, size_t ws_size,
                              hipStream_t stream) {
  const float* x  = (const float*)d_in[0];
  const float* Wq = (const float*)d_in[1];
  const float* Wk = (const float*)d_in[2];
  const float* Wv = (const float*)d_in[3];
  const float* Wo = (const float*)d_in[4];
  const float* bo = (const float*)d_in[5];

  unsigned short* xb = (unsigned short*)d_ws;
  unsigned short* wt = xb + (size_t)SEQ * DM;
  unsigned short* Qb = wt + (size_t)4 * DM * DM;
  unsigned short* Kb = Qb + (size_t)SEQ * DM;
  unsigned short* Vt = Kb + (size_t)SEQ * DM;
  unsigned short* cx = Vt + (size_t)SEQ * DM;

  const float qscale = 1.4426950408889634f / 8.0f;  // log2(e)/sqrt(HD)

  k_cvt<<<(SEQ * DM) / 1024, 256, 0, stream>>>(x, xb);
  k_tw<<<dim3(24, 24, 4), 256, 0, stream>>>(Wq, Wk, Wv, Wo, wt);
  dim3 gg(SEQ / 128, DM / 64);
  k_gemm<0><<<gg, 256, 0, stream>>>(xb, wt, Qb, nullptr, qscale);
  k_gemm<0><<<gg, 256, 0, stream>>>(xb, wt + (size_t)DM * DM, Kb, nullptr, 1.0f);
  k_gemm<1><<<gg, 256, 0, stream>>>(xb, wt + (size_t)2 * DM * DM, Vt, nullptr, 1.0f);
  k_attn<<<dim3(SEQ / 32, NH), 128, 0, stream>>>(Qb, Kb, Vt, cx);
  k_gemm<2><<<gg, 256, 0, stream>>>(cx, wt + (size_t)3 * DM * DM, d_out, bo, 1.0f);
}

// Round 4
// 161.253 us; speedup vs baseline: 2.5012x; 1.4862x over previous
//
#include <hip/hip_runtime.h>
#include <stdint.h>

#define SEQ 4096
#define DM 768
#define NH 12
#define HD 64

typedef __attribute__((ext_vector_type(8))) short bf8;
typedef __attribute__((ext_vector_type(4))) float f4;
typedef __attribute__((ext_vector_type(16))) float f32x16;

static __device__ __forceinline__ f4 mfma_bf16(bf8 a, bf8 b, f4 c) {
  return __builtin_amdgcn_mfma_f32_16x16x32_bf16(a, b, c, 0, 0, 0);
}
static __device__ __forceinline__ f32x16 mfma32(bf8 a, bf8 b, f32x16 c) {
  return __builtin_amdgcn_mfma_f32_32x32x16_bf16(a, b, c, 0, 0, 0);
}

// RNE float->bf16 (bit pattern)
static __device__ __forceinline__ unsigned short f2bf(float f) {
  unsigned int u = __float_as_uint(f);
  u += 0x7FFFu + ((u >> 16) & 1u);
  return (unsigned short)(u >> 16);
}

// packed f32 pair -> bf16 pair (lo in low 16, hi in high 16)
static __device__ __forceinline__ unsigned int cvtpk(float lo, float hi) {
  unsigned int r;
  asm("v_cvt_pk_bf16_f32 %0, %1, %2" : "=v"(r) : "v"(lo), "v"(hi));
  return r;
}

static __device__ __forceinline__ void gload_lds16(const void* g, void* l) {
  __builtin_amdgcn_global_load_lds(
      (const __attribute__((address_space(1))) void*)g,
      (__attribute__((address_space(3))) void*)l, 16, 0, 0);
}

// ---- cast x (fp32) -> bf16 -----------------------------------------------
__global__ __launch_bounds__(256) void k_cvt(const float* __restrict__ x,
                                             unsigned short* __restrict__ xb) {
  int i = (blockIdx.x * 256 + threadIdx.x) * 4;
  float4 v = *reinterpret_cast<const float4*>(x + i);
  ushort4 o;
  o.x = f2bf(v.x); o.y = f2bf(v.y); o.z = f2bf(v.z); o.w = f2bf(v.w);
  *reinterpret_cast<ushort4*>(xb + i) = o;
}

// ---- transpose+cast weights: WT[z][n][k] = bf16(W[k][n]) -----------------
__global__ __launch_bounds__(256) void k_tw(const float* __restrict__ w0,
                                            const float* __restrict__ w1,
                                            const float* __restrict__ w2,
                                            const float* __restrict__ w3,
                                            unsigned short* __restrict__ wt) {
  const float* W = blockIdx.z == 0 ? w0 : blockIdx.z == 1 ? w1
                 : blockIdx.z == 2 ? w2 : w3;
  unsigned short* WT = wt + (size_t)blockIdx.z * DM * DM;
  __shared__ float t[32][33];
  int c0 = blockIdx.x * 32, r0 = blockIdx.y * 32;
  int lx = threadIdx.x & 31, ly = threadIdx.x >> 5;
#pragma unroll
  for (int rr = 0; rr < 32; rr += 8)
    t[ly + rr][lx] = W[(size_t)(r0 + ly + rr) * DM + c0 + lx];
  __syncthreads();
#pragma unroll
  for (int rr = 0; rr < 32; rr += 8)
    WT[(size_t)(c0 + ly + rr) * DM + r0 + lx] = f2bf(t[lx][ly + rr]);
}

// ---- bf16 MFMA GEMM: C[4096][768] = A[4096][768] @ Bt[768][768]^T --------
// MODE 0: store bf16 [row][768] * scale   (Q gets softmax scale folded in)
// MODE 1: store bf16 transposed Vt[col][4096]
// MODE 2: store fp32 [row][768] + bias[col]
template <int MODE>
__global__ __launch_bounds__(256) void k_gemm(const unsigned short* __restrict__ A,
                                              const unsigned short* __restrict__ Bt,
                                              void* __restrict__ Cout,
                                              const float* __restrict__ bias,
                                              float scale) {
  constexpr int K = DM;
  __shared__ unsigned short sA[128 * 32];
  __shared__ unsigned short sB[64 * 32];
  const int t = threadIdx.x, lane = t & 63, w = t >> 6;
  const int wr = w >> 1, wc = w & 1;
  const int c = lane & 15, g = lane >> 4;
  const int brow = blockIdx.x * 128, bcol = blockIdx.y * 64;
  f4 acc[4][2] = {};
  for (int k0 = 0; k0 < K; k0 += 32) {
#pragma unroll
    for (int i = 0; i < 2; ++i) {
      int slot = w * 2 + i;
      int chunk = slot * 64 + lane;
      int row = chunk >> 2;
      int sl = (chunk & 3) ^ ((row >> 1) & 3);
      gload_lds16(A + (size_t)(brow + row) * K + k0 + sl * 8, &sA[slot * 512]);
    }
    {
      int chunk = w * 64 + lane;
      int row = chunk >> 2;
      int sl = (chunk & 3) ^ ((row >> 1) & 3);
      gload_lds16(Bt + (size_t)(bcol + row) * K + k0 + sl * 8, &sB[w * 512]);
    }
    __syncthreads();
    bf8 af[4], bfr[2];
#pragma unroll
    for (int m = 0; m < 4; ++m) {
      int row = wr * 64 + m * 16 + c;
      int off = row * 64 + ((g * 16) ^ (((row >> 1) & 3) << 4));
      af[m] = *reinterpret_cast<const bf8*>(reinterpret_cast<const char*>(sA) + off);
    }
#pragma unroll
    for (int n = 0; n < 2; ++n) {
      int row = wc * 32 + n * 16 + c;
      int off = row * 64 + ((g * 16) ^ (((row >> 1) & 3) << 4));
      bfr[n] = *reinterpret_cast<const bf8*>(reinterpret_cast<const char*>(sB) + off);
    }
#pragma unroll
    for (int m = 0; m < 4; ++m)
#pragma unroll
      for (int n = 0; n < 2; ++n)
        acc[m][n] = mfma_bf16(af[m], bfr[n], acc[m][n]);
    __syncthreads();
  }
#pragma unroll
  for (int m = 0; m < 4; ++m) {
#pragma unroll
    for (int n = 0; n < 2; ++n) {
      int col = bcol + wc * 32 + n * 16 + c;
      int row0 = brow + wr * 64 + m * 16 + g * 4;
      if (MODE == 0) {
        unsigned short* C = (unsigned short*)Cout;
#pragma unroll
        for (int r = 0; r < 4; ++r)
          C[(size_t)(row0 + r) * DM + col] = f2bf(acc[m][n][r] * scale);
      } else if (MODE == 1) {
        unsigned short* C = (unsigned short*)Cout;
        ushort4 p;
        p.x = f2bf(acc[m][n][0]); p.y = f2bf(acc[m][n][1]);
        p.z = f2bf(acc[m][n][2]); p.w = f2bf(acc[m][n][3]);
        *reinterpret_cast<ushort4*>(C + (size_t)col * SEQ + row0) = p;
      } else {
        float* C = (float*)Cout;
#pragma unroll
        for (int r = 0; r < 4; ++r)
          C[(size_t)(row0 + r) * DM + col] = acc[m][n][r] + bias[col];
      }
    }
  }
}

// ---- causal flash attention, paired q-tiles + split-K x4 -----------------
// Block = 4 waves. Handles q-tiles {b, 127-b} sequentially -> uniform 129
// tiles/block. Each wave strides k-tiles by 4; 4-way merge via LDS.
// K prefetched one tile ahead (register dbuf); V issued at step start.
// Qb pre-scaled by log2(e)/sqrt(HD). Vt: [12*64][4096].
__global__ __launch_bounds__(256, 3) void k_attn(const unsigned short* __restrict__ Qb,
                                                 const unsigned short* __restrict__ Kb,
                                                 const unsigned short* __restrict__ Vt,
                                                 unsigned short* __restrict__ ctx) {
  const int tid = threadIdx.x;
  const int lane = tid & 63;
  const int w = tid >> 6;  // split-K wave index, 0..3
  const int ql = lane & 31, hi = lane >> 5;
  const int h = blockIdx.y;
  const size_t hd = (size_t)h * HD;

  __shared__ float sO[4][64][32];
  __shared__ float sM[4][32];
  __shared__ float sL[4][32];

  auto loadK = [&](bf8 (&kf)[4], int t) {
    const unsigned short* kp = Kb + (size_t)(t * 32 + ql) * DM + hd + hi * 8;
#pragma unroll
    for (int d = 0; d < 4; ++d)
      kf[d] = *reinterpret_cast<const bf8*>(kp + d * 16);
  };

  auto phase = [&](int qt) {
    const int qg = qt * 32 + ql;
    // Q as B-fragments: col=q=lane&31, k(d)=8*hi+j
    bf8 qf[4];
    {
      const unsigned short* qp = Qb + (size_t)qg * DM + hd + hi * 8;
#pragma unroll
      for (int d = 0; d < 4; ++d)
        qf[d] = *reinterpret_cast<const bf8*>(qp + d * 16);
    }
    f32x16 o0 = {}, o1 = {};
    float m = -1e30f, l = 0.f;

    auto step = [&](bf8 (&kf)[4], int t) {
      const int k0 = t * 32;
      // V^T A-fragments: issue loads first (consumed after softmax)
      bf8 vf[2][2];
      {
        const unsigned short* vp = Vt + (hd + ql) * SEQ + k0 + hi * 8;
#pragma unroll
        for (int kh = 0; kh < 2; ++kh) {
          vf[kh][0] = *reinterpret_cast<const bf8*>(vp + kh * 16);
          vf[kh][1] = *reinterpret_cast<const bf8*>(vp + (size_t)32 * SEQ + kh * 16);
        }
      }
      // S^T[k][q] = K(32k x 16d) x Q(16d x 32q)
      f32x16 s = {};
#pragma unroll
      for (int d = 0; d < 4; ++d)
        s = mfma32(kf[d], qf[d], s);
      if (t == qt) {  // diagonal tile: causal mask
#pragma unroll
        for (int r = 0; r < 16; ++r) {
          int kr = k0 + (r & 3) + 8 * (r >> 2) + 4 * hi;
          s[r] = (kr > qg) ? -1e30f : s[r];
        }
      }
      // online softmax (scores already in log2 scale)
      float tm = s[0];
#pragma unroll
      for (int r = 1; r < 16; ++r) tm = fmaxf(tm, s[r]);
      tm = fmaxf(tm, __shfl_xor(tm, 32));
      float mn = fmaxf(m, tm);
      float al = __builtin_amdgcn_exp2f(m - mn);
      m = mn;
      float p[16];
      float ls = 0.f;
#pragma unroll
      for (int r = 0; r < 16; ++r) {
        p[r] = __builtin_amdgcn_exp2f(s[r] - mn);
        ls += p[r];
      }
      ls += __shfl_xor(ls, 32);
      l = l * al + ls;
#pragma unroll
      for (int r = 0; r < 16; ++r) { o0[r] *= al; o1[r] *= al; }
      // P^T -> B-fragments via cvt_pk + permlane32_swap.
      bf8 pf[2];
#pragma unroll
      for (int kh = 0; kh < 2; ++kh) {
        unsigned int A0 = cvtpk(p[kh * 8 + 0], p[kh * 8 + 1]);
        unsigned int A1 = cvtpk(p[kh * 8 + 2], p[kh * 8 + 3]);
        unsigned int B0 = cvtpk(p[kh * 8 + 4], p[kh * 8 + 5]);
        unsigned int B1 = cvtpk(p[kh * 8 + 6], p[kh * 8 + 7]);
        asm volatile("v_permlane32_swap_b32 %0, %1" : "+v"(A0), "+v"(B0));
        asm volatile("v_permlane32_swap_b32 %0, %1" : "+v"(A1), "+v"(B1));
        uint4 wds = {A0, A1, B0, B1};
        pf[kh] = *reinterpret_cast<bf8*>(&wds);
      }
      // O^T[d][q] += V^T(32d x 16k) x P^T(16k x 32q)
#pragma unroll
      for (int kh = 0; kh < 2; ++kh) {
        o0 = mfma32(vf[kh][0], pf[kh], o0);
        o1 = mfma32(vf[kh][1], pf[kh], o1);
      }
    };

    // pipelined loop over this wave's tiles: t = w + 4*i
    const int nt = (qt >= w) ? ((qt - w) >> 2) + 1 : 0;
    bf8 kA[4], kB[4];
    if (nt > 0) loadK(kA, w);
    int i = 0;
    for (; i + 2 <= nt; i += 2) {
      loadK(kB, w + (i + 1) * 4);
      step(kA, w + i * 4);
      if (i + 2 < nt) loadK(kA, w + (i + 2) * 4);
      step(kB, w + (i + 1) * 4);
    }
    if (i < nt) step(kA, w + i * 4);

    // ---- 4-way split-K merge via LDS ----
#pragma unroll
    for (int r = 0; r < 16; ++r) {
      int dr = (r & 3) + 8 * (r >> 2) + 4 * hi;
      sO[w][dr][ql] = o0[r];
      sO[w][32 + dr][ql] = o1[r];
    }
    if (hi == 0) { sM[w][ql] = m; sL[w][ql] = l; }
    __syncthreads();
    {
      const int q = tid & 31;
      const int dblk = tid >> 5;  // 0..7, 8 d-values each
      float m0 = sM[0][q], m1 = sM[1][q], m2 = sM[2][q], m3 = sM[3][q];
      float mn = fmaxf(fmaxf(m0, m1), fmaxf(m2, m3));
      float a0 = __builtin_amdgcn_exp2f(m0 - mn);
      float a1 = __builtin_amdgcn_exp2f(m1 - mn);
      float a2 = __builtin_amdgcn_exp2f(m2 - mn);
      float a3 = __builtin_amdgcn_exp2f(m3 - mn);
      float inv = 1.f / (a0 * sL[0][q] + a1 * sL[1][q] + a2 * sL[2][q] + a3 * sL[3][q]);
      a0 *= inv; a1 *= inv; a2 *= inv; a3 *= inv;
      unsigned short* cp = ctx + (size_t)(qt * 32 + q) * DM + hd + dblk * 8;
#pragma unroll
      for (int j = 0; j < 8; j += 2) {
        int d = dblk * 8 + j;
        float v0 = sO[0][d][q] * a0 + sO[1][d][q] * a1 + sO[2][d][q] * a2 + sO[3][d][q] * a3;
        float v1 = sO[0][d + 1][q] * a0 + sO[1][d + 1][q] * a1 + sO[2][d + 1][q] * a2 + sO[3][d + 1][q] * a3;
        *reinterpret_cast<unsigned int*>(cp + j) = cvtpk(v0, v1);
      }
    }
    __syncthreads();
  };

  phase((int)blockIdx.x);
  phase(127 - (int)blockIdx.x);
}

extern "C" void kernel_launch(void* const* d_in, const int* in_sizes, int n_in,
                              void* d_out, int out_size, void* d_ws, size_t ws_size,
                              hipStream_t stream) {
  const float* x  = (const float*)d_in[0];
  const float* Wq = (const float*)d_in[1];
  const float* Wk = (const float*)d_in[2];
  const float* Wv = (const float*)d_in[3];
  const float* Wo = (const float*)d_in[4];
  const float* bo = (const float*)d_in[5];

  unsigned short* xb = (unsigned short*)d_ws;
  unsigned short* wt = xb + (size_t)SEQ * DM;
  unsigned short* Qb = wt + (size_t)4 * DM * DM;
  unsigned short* Kb = Qb + (size_t)SEQ * DM;
  unsigned short* Vt = Kb + (size_t)SEQ * DM;
  unsigned short* cx = Vt + (size_t)SEQ * DM;

  const float qscale = 1.4426950408889634f / 8.0f;  // log2(e)/sqrt(HD)

  k_cvt<<<(SEQ * DM) / 1024, 256, 0, stream>>>(x, xb);
  k_tw<<<dim3(24, 24, 4), 256, 0, stream>>>(Wq, Wk, Wv, Wo, wt);
  dim3 gg(SEQ / 128, DM / 64);
  k_gemm<0><<<gg, 256, 0, stream>>>(xb, wt, Qb, nullptr, qscale);
  k_gemm<0><<<gg, 256, 0, stream>>>(xb, wt + (size_t)DM * DM, Kb, nullptr, 1.0f);
  k_gemm<1><<<gg, 256, 0, stream>>>(xb, wt + (size_t)2 * DM * DM, Vt, nullptr, 1.0f);
  k_attn<<<dim3(SEQ / 64, NH), 256, 0, stream>>>(Qb, Kb, Vt, cx);
  k_gemm<2><<<gg, 256, 0, stream>>>(cx, wt + (size_t)3 * DM * DM, d_out, bo, 1.0f);
}